// Round 7
// baseline (1497.255 us; speedup 1.0000x reference)
//
#include <hip/hip_runtime.h>
#include <hip/hip_bf16.h>
#include <stdint.h>

#define TT   8192   // B*S tokens
#define DD   2048
#define MM   2048
#define NE   8

typedef float f32x4 __attribute__((ext_vector_type(4)));
typedef short s16x8 __attribute__((ext_vector_type(8)));
typedef unsigned int u32;

static __device__ __forceinline__ short f2bf(float f) {
  __hip_bfloat16 h = __float2bfloat16(f);
  short s;
  __builtin_memcpy(&s, &h, 2);
  return s;
}

static __device__ __forceinline__ void gload_lds16(const short* g, short* lds) {
  __builtin_amdgcn_global_load_lds(
      (const __attribute__((address_space(1))) u32*)g,
      (__attribute__((address_space(3))) u32*)lds, 16, 0, 0);
}

// ---------------- fp32 -> bf16 conversion (x) ----------------
__global__ __launch_bounds__(256) void cvt_kernel(const float* __restrict__ in,
                                                  short* __restrict__ out, size_t n) {
  size_t idx = ((size_t)blockIdx.x * 256 + threadIdx.x) * 8;
  size_t stride = (size_t)gridDim.x * 256 * 8;
  for (size_t i = idx; i < n; i += stride) {
    f32x4 a = *(const f32x4*)(in + i);
    f32x4 b = *(const f32x4*)(in + i + 4);
    s16x8 v;
    v[0]=f2bf(a[0]); v[1]=f2bf(a[1]); v[2]=f2bf(a[2]); v[3]=f2bf(a[3]);
    v[4]=f2bf(b[0]); v[5]=f2bf(b[1]); v[6]=f2bf(b[2]); v[7]=f2bf(b[3]);
    *(s16x8*)(out + i) = v;
  }
}

// ---------------- fp32 -> bf16 transposing conversion (weights) ----------------
__global__ __launch_bounds__(256) void tcvt_kernel(
    const float* __restrict__ w0, const float* __restrict__ w1, const float* __restrict__ w2,
    short* __restrict__ o0, short* __restrict__ o1, short* __restrict__ o2) {
  __shared__ short tile[64][65];
  const int bz = blockIdx.z;
  const float* in; short* out;
  if (bz < 8)       { in = w0; out = o0; }
  else if (bz < 16) { in = w1; out = o1; }
  else              { in = w2; out = o2; }
  const int ex = bz & 7;
  const float* src = in + (size_t)ex * DD * MM;
  short* dst = out + (size_t)ex * DD * MM;
  const int r0 = blockIdx.y * 64;
  const int c0 = blockIdx.x * 64;
  const int t = threadIdx.x;
  const int rr = t >> 4, cc = (t & 15) * 4;
  #pragma unroll
  for (int i = 0; i < 4; i++) {
    int row = rr + i * 16;
    f32x4 v = *(const f32x4*)(src + (size_t)(r0 + row) * MM + c0 + cc);
    tile[cc + 0][row] = f2bf(v[0]);
    tile[cc + 1][row] = f2bf(v[1]);
    tile[cc + 2][row] = f2bf(v[2]);
    tile[cc + 3][row] = f2bf(v[3]);
  }
  __syncthreads();
  const int orow = t >> 2, c8 = (t & 3) * 16;
  s16x8 v0, v1;
  #pragma unroll
  for (int i = 0; i < 8; i++) { v0[i] = tile[orow][c8 + i]; v1[i] = tile[orow][c8 + 8 + i]; }
  short* dp = dst + (size_t)(c0 + orow) * DD + r0 + c8;
  *(s16x8*)(dp) = v0;
  *(s16x8*)(dp + 8) = v1;
}

// ---------------- gate: fp32 logits, top-2, softmax ----------------
__global__ __launch_bounds__(256) void gate_kernel(const float* __restrict__ x,
    const float* __restrict__ gk, int* __restrict__ counts,
    int* __restrict__ tkidx, float* __restrict__ tkw) {
  int t = blockIdx.x;
  const float* xr = x + (size_t)t * DD;
  float acc[NE];
  #pragma unroll
  for (int e = 0; e < NE; e++) acc[e] = 0.f;
  for (int d = threadIdx.x; d < DD; d += 256) {
    float xv = xr[d];
    const float* g = gk + (size_t)d * NE;
    #pragma unroll
    for (int e = 0; e < NE; e++) acc[e] += xv * g[e];
  }
  #pragma unroll
  for (int e = 0; e < NE; e++) {
    #pragma unroll
    for (int off = 32; off >= 1; off >>= 1)
      acc[e] += __shfl_xor(acc[e], off, 64);
  }
  __shared__ float red[4][NE];
  int wid = threadIdx.x >> 6;
  int lane = threadIdx.x & 63;
  if (lane == 0) {
    #pragma unroll
    for (int e = 0; e < NE; e++) red[wid][e] = acc[e];
  }
  __syncthreads();
  if (threadIdx.x == 0) {
    float l[NE];
    #pragma unroll
    for (int e = 0; e < NE; e++) l[e] = red[0][e] + red[1][e] + red[2][e] + red[3][e];
    int i1 = 0; float v1 = l[0];
    #pragma unroll
    for (int e = 1; e < NE; e++) if (l[e] > v1) { v1 = l[e]; i1 = e; }
    int i2 = -1; float v2 = -1e30f;
    #pragma unroll
    for (int e = 0; e < NE; e++) if (e != i1 && l[e] > v2) { v2 = l[e]; i2 = e; }
    float p = __expf(v2 - v1);
    float inv = 1.f / (1.f + p);
    tkidx[t*2]   = i1; tkidx[t*2+1] = i2;
    tkw[t*2]     = inv; tkw[t*2+1]  = p * inv;
    atomicAdd(&counts[i1], 1);
    atomicAdd(&counts[i2], 1);
  }
}

// ---------------- scatter into per-expert compact lists (+ slot map) ----------------
__global__ __launch_bounds__(256) void scatter_kernel(const int* __restrict__ counts,
    int* __restrict__ offsets, const int* __restrict__ tkidx,
    const float* __restrict__ tkw, int* __restrict__ ltok, float* __restrict__ lwt,
    int* __restrict__ slots) {
  __shared__ int soff[NE];
  __shared__ int scur[NE];
  if (threadIdx.x == 0) {
    int s = 0;
    for (int e = 0; e < NE; e++) { offsets[e] = s; soff[e] = s; s += counts[e]; scur[e] = 0; }
    offsets[NE] = s;
  }
  __syncthreads();
  for (int i = threadIdx.x; i < TT * 2; i += 256) {
    int e = tkidx[i];
    int pos = atomicAdd(&scur[e], 1);
    int dst = soff[e] + pos;
    ltok[dst] = i >> 1;
    lwt[dst]  = tkw[i];
    slots[i]  = dst;
  }
}

// ---------------- combine: out[t] = comb[slot0] + comb[slot1] ----------------
__global__ __launch_bounds__(256) void combine_kernel(const float* __restrict__ comb,
    const int* __restrict__ slots, float* __restrict__ out) {
  const int t = blockIdx.x;
  const int s0 = slots[2 * t], s1 = slots[2 * t + 1];
  const f32x4* p0 = (const f32x4*)(comb + (size_t)s0 * DD);
  const f32x4* p1 = (const f32x4*)(comb + (size_t)s1 * DD);
  f32x4* po = (f32x4*)(out + (size_t)t * DD);
  #pragma unroll
  for (int i = 0; i < 2; i++) {
    int idx = threadIdx.x + i * 256;
    po[idx] = p0[idx] + p1[idx];
  }
}

// ---------------- segment lookup ----------------
__device__ __forceinline__ void find_seg(const int* __restrict__ offsets, int tile, int bm,
                                         int& e, int& row0, int& rows, int& seg) {
  e = -1; row0 = 0; rows = 0; seg = 0;
  int accT = 0, prev = offsets[0];
  #pragma unroll
  for (int i = 0; i < NE; i++) {
    int nxt = offsets[i+1];
    int cnt = nxt - prev;
    int nt = (cnt + bm - 1) / bm;
    if (e < 0 && tile < accT + nt) { e = i; row0 = (tile - accT) * bm; rows = cnt; seg = prev; }
    accT += nt; prev = nxt;
  }
}

// XCD-chunked blockIdx swizzle (bijective: nwg % 8 == 0), x-fast decode.
__device__ __forceinline__ void xcd_map(int& tile, int& nyi) {
  const int nx = gridDim.x;
  const int nwg = nx * gridDim.y;
  const int bid = blockIdx.y * nx + blockIdx.x;
  const int cpx = nwg >> 3;
  const int s = (bid & 7) * cpx + (bid >> 3);
  tile = s % nx;
  nyi  = s / nx;
}

// ================= FAST PATH (round-3 structure + swizzle + occupancy) =================
// 128x128 tile, BK=64, 256 threads (2x2 waves, 64x64 wave tile, 4x4 16x16x32 frags).
// LDS linear [128][64] shorts; swizzle: short-offset s holds G[row][s ^ ((row&7)*8)].
#define MAXT_F 136

__global__ __launch_bounds__(256, 3) void gemm1_fast(
    const short* __restrict__ xbf,
    const short* __restrict__ w0t, const short* __restrict__ w1t,
    const int* __restrict__ offsets,
    const int* __restrict__ ltok, const float* __restrict__ lwt,
    short* __restrict__ hbuf) {
  __shared__ short As[128 * 64];
  __shared__ short B0s[128 * 64];
  __shared__ short B1s[128 * 64];
  __shared__ float w_s[128];

  int tile, nyi;
  xcd_map(tile, nyi);
  const int n0 = nyi * 128;
  int e, row0, rows, seg;
  find_seg(offsets, tile, 128, e, row0, rows, seg);
  if (e < 0) return;

  const int tid = threadIdx.x;
  const int lane = tid & 63, wid = tid >> 6;
  if (tid < 128) {
    int gr = row0 + tid;
    w_s[tid] = (gr < rows) ? lwt[seg + gr] : 0.f;
  }

  const int swz = ((lane & 7) ^ (lane >> 3)) * 8;   // pre-swizzled source offset (shorts)
  const short* abase[4];
  const short* b0base[4];
  const short* b1base[4];
  #pragma unroll
  for (int c = 0; c < 4; c++) {
    int chunk = wid * 4 + c;
    int r = chunk * 8 + (lane >> 3);
    int gr = row0 + r; if (gr >= rows) gr = rows - 1;
    int tok = ltok[seg + gr];
    abase[c]  = xbf + (size_t)tok * DD + swz;
    int n = n0 + r;
    b0base[c] = w0t + ((size_t)e * MM + n) * DD + swz;
    b1base[c] = w1t + ((size_t)e * MM + n) * DD + swz;
  }

  const int wr = wid >> 1, wc = wid & 1;
  const int lr = lane & 15;
  const int kq = (lane >> 4) * 8;

  f32x4 acc0[4][4], acc1[4][4];
  #pragma unroll
  for (int i = 0; i < 4; i++)
    #pragma unroll
    for (int j = 0; j < 4; j++) { acc0[i][j] = 0.f; acc1[i][j] = 0.f; }

  for (int k0 = 0; k0 < DD; k0 += 64) {
    #pragma unroll
    for (int c = 0; c < 4; c++) {
      int chunk = wid * 4 + c;
      gload_lds16(abase[c]  + k0, As  + chunk * 512);
      gload_lds16(b0base[c] + k0, B0s + chunk * 512);
      gload_lds16(b1base[c] + k0, B1s + chunk * 512);
    }
    __syncthreads();

    #pragma unroll
    for (int ks = 0; ks < 2; ks++) {
      s16x8 a[4], b0[4], b1[4];
      #pragma unroll
      for (int mi = 0; mi < 4; mi++) {
        int row = wr * 64 + mi * 16 + lr;
        int koff = (ks * 32 + kq) ^ ((row & 7) * 8);
        a[mi] = *(const s16x8*)&As[row * 64 + koff];
      }
      #pragma unroll
      for (int ni = 0; ni < 4; ni++) {
        int row = wc * 64 + ni * 16 + lr;
        int koff = (ks * 32 + kq) ^ ((row & 7) * 8);
        b0[ni] = *(const s16x8*)&B0s[row * 64 + koff];
        b1[ni] = *(const s16x8*)&B1s[row * 64 + koff];
      }
      #pragma unroll
      for (int mi = 0; mi < 4; mi++)
        #pragma unroll
        for (int ni = 0; ni < 4; ni++) {
          acc0[mi][ni] = __builtin_amdgcn_mfma_f32_16x16x32_bf16(a[mi], b0[ni], acc0[mi][ni], 0, 0, 0);
          acc1[mi][ni] = __builtin_amdgcn_mfma_f32_16x16x32_bf16(a[mi], b1[ni], acc1[mi][ni], 0, 0, 0);
        }
    }
    __syncthreads();
  }

  const int lq = lane >> 4;
  #pragma unroll
  for (int mi = 0; mi < 4; mi++) {
    #pragma unroll
    for (int jj = 0; jj < 4; jj++) {
      int r = wr * 64 + mi * 16 + lq * 4 + jj;
      int gr = row0 + r;
      if (gr < rows) {
        float wgt = w_s[r];
        size_t hrow = (size_t)(seg + gr) * MM + n0;
        #pragma unroll
        for (int ni = 0; ni < 4; ni++) {
          int c = wc * 64 + ni * 16 + lr;
          float g = acc0[mi][ni][jj];
          float u = acc1[mi][ni][jj];
          float act = g / (1.f + __expf(-g));
          hbuf[hrow + c] = f2bf(act * u * wgt);
        }
      }
    }
  }
}

__global__ __launch_bounds__(256, 3) void gemm2_fast(
    const short* __restrict__ hbuf,
    const short* __restrict__ wot,
    const int* __restrict__ offsets,
    float* __restrict__ comb) {
  __shared__ short As[128 * 64];
  __shared__ short Bs[128 * 64];

  int tile, nyi;
  xcd_map(tile, nyi);
  const int n0 = nyi * 128;
  int e, row0, rows, seg;
  find_seg(offsets, tile, 128, e, row0, rows, seg);
  if (e < 0) return;

  const int tid = threadIdx.x;
  const int lane = tid & 63, wid = tid >> 6;

  const int swz = ((lane & 7) ^ (lane >> 3)) * 8;
  const short* abase[4];
  const short* bbase[4];
  #pragma unroll
  for (int c = 0; c < 4; c++) {
    int chunk = wid * 4 + c;
    int r = chunk * 8 + (lane >> 3);
    int gr = row0 + r; if (gr >= rows) gr = rows - 1;
    abase[c] = hbuf + (size_t)(seg + gr) * MM + swz;
    int n = n0 + r;
    bbase[c] = wot + ((size_t)e * DD + n) * MM + swz;
  }

  const int wr = wid >> 1, wc = wid & 1;
  const int lr = lane & 15;
  const int kq = (lane >> 4) * 8;

  f32x4 acc[4][4];
  #pragma unroll
  for (int i = 0; i < 4; i++)
    #pragma unroll
    for (int j = 0; j < 4; j++) acc[i][j] = 0.f;

  for (int k0 = 0; k0 < MM; k0 += 64) {
    #pragma unroll
    for (int c = 0; c < 4; c++) {
      int chunk = wid * 4 + c;
      gload_lds16(abase[c] + k0, As + chunk * 512);
      gload_lds16(bbase[c] + k0, Bs + chunk * 512);
    }
    __syncthreads();

    #pragma unroll
    for (int ks = 0; ks < 2; ks++) {
      s16x8 a[4], b[4];
      #pragma unroll
      for (int mi = 0; mi < 4; mi++) {
        int row = wr * 64 + mi * 16 + lr;
        int koff = (ks * 32 + kq) ^ ((row & 7) * 8);
        a[mi] = *(const s16x8*)&As[row * 64 + koff];
      }
      #pragma unroll
      for (int ni = 0; ni < 4; ni++) {
        int row = wc * 64 + ni * 16 + lr;
        int koff = (ks * 32 + kq) ^ ((row & 7) * 8);
        b[ni] = *(const s16x8*)&Bs[row * 64 + koff];
      }
      #pragma unroll
      for (int mi = 0; mi < 4; mi++)
        #pragma unroll
        for (int ni = 0; ni < 4; ni++)
          acc[mi][ni] = __builtin_amdgcn_mfma_f32_16x16x32_bf16(a[mi], b[ni], acc[mi][ni], 0, 0, 0);
    }
    __syncthreads();
  }

  const int lq = lane >> 4;
  #pragma unroll
  for (int mi = 0; mi < 4; mi++) {
    #pragma unroll
    for (int jj = 0; jj < 4; jj++) {
      int r = wr * 64 + mi * 16 + lq * 4 + jj;
      int gr = row0 + r;
      if (gr < rows) {
        size_t orow = (size_t)(seg + gr) * DD + n0;
        #pragma unroll
        for (int ni = 0; ni < 4; ni++) {
          int c = wc * 64 + ni * 16 + lr;
          comb[orow + c] = acc[mi][ni][jj];
        }
      }
    }
  }
}

// ---------------- launcher ----------------
extern "C" void kernel_launch(void* const* d_in, const int* in_sizes, int n_in,
                              void* d_out, int out_size, void* d_ws, size_t ws_size,
                              hipStream_t stream) {
  const float* x   = (const float*)d_in[0];
  const float* gk  = (const float*)d_in[1];
  const float* wi0 = (const float*)d_in[2];
  const float* wi1 = (const float*)d_in[3];
  const float* wo  = (const float*)d_in[4];
  float* out = (float*)d_out;

  char* w = (char*)d_ws;
  int*   counts  = (int*)(w);
  int*   offsets = (int*)(w + 256);
  int*   tkidx   = (int*)(w + 1024);
  float* tkw     = (float*)(w + 1024 + 65536);
  int*   ltok    = (int*)(w + 1024 + 2*65536);
  float* lwt     = (float*)(w + 1024 + 3*65536);
  int*   slots   = (int*)(w + 1024 + 4*65536);
  short* xbf  = (short*)(w + 524288);
  short* hbuf = xbf + (size_t)TT * DD;                     // 2T x M bf16
  short* w0t  = hbuf + (size_t)2 * TT * MM;
  short* w1t  = w0t + (size_t)NE * DD * MM;
  short* wot  = w1t + (size_t)NE * DD * MM;
  float* comb = (float*)w0t;   // reuse w0t+w1t region (128 MB) after gemm1

  hipMemsetAsync(counts, 0, 64, stream);

  cvt_kernel<<<1024, 256, 0, stream>>>(x, xbf, (size_t)TT * DD);
  gate_kernel<<<TT, 256, 0, stream>>>(x, gk, counts, tkidx, tkw);
  scatter_kernel<<<1, 256, 0, stream>>>(counts, offsets, tkidx, tkw, ltok, lwt, slots);
  tcvt_kernel<<<dim3(MM/64, DD/64, 24), 256, 0, stream>>>(wi0, wi1, wo, w0t, w1t, wot);

  gemm1_fast<<<dim3(MAXT_F, MM/128), 256, 0, stream>>>(xbf, w0t, w1t, offsets, ltok, lwt, hbuf);
  gemm2_fast<<<dim3(MAXT_F, DD/128), 256, 0, stream>>>(hbuf, wot, offsets, comb);
  combine_kernel<<<TT, 256, 0, stream>>>(comb, slots, out);
}

// Round 8
// 911.070 us; speedup vs baseline: 1.6434x; 1.6434x over previous
//
#include <hip/hip_runtime.h>
#include <hip/hip_bf16.h>
#include <stdint.h>

#define TT   8192   // B*S tokens
#define DD   2048
#define MM   2048
#define NE   8

typedef float f32x4 __attribute__((ext_vector_type(4)));
typedef short s16x8 __attribute__((ext_vector_type(8)));
typedef unsigned int u32;

static __device__ __forceinline__ short f2bf(float f) {
  __hip_bfloat16 h = __float2bfloat16(f);
  short s;
  __builtin_memcpy(&s, &h, 2);
  return s;
}

static __device__ __forceinline__ void gload_lds16(const short* g, short* lds) {
  __builtin_amdgcn_global_load_lds(
      (const __attribute__((address_space(1))) u32*)g,
      (__attribute__((address_space(3))) u32*)lds, 16, 0, 0);
}

// ---------------- fp32 -> bf16 conversion (x) ----------------
__global__ __launch_bounds__(256) void cvt_kernel(const float* __restrict__ in,
                                                  short* __restrict__ out, size_t n) {
  size_t idx = ((size_t)blockIdx.x * 256 + threadIdx.x) * 8;
  size_t stride = (size_t)gridDim.x * 256 * 8;
  for (size_t i = idx; i < n; i += stride) {
    f32x4 a = *(const f32x4*)(in + i);
    f32x4 b = *(const f32x4*)(in + i + 4);
    s16x8 v;
    v[0]=f2bf(a[0]); v[1]=f2bf(a[1]); v[2]=f2bf(a[2]); v[3]=f2bf(a[3]);
    v[4]=f2bf(b[0]); v[5]=f2bf(b[1]); v[6]=f2bf(b[2]); v[7]=f2bf(b[3]);
    *(s16x8*)(out + i) = v;
  }
}

// ---------------- fp32 -> bf16 transposing conversion (weights) ----------------
__global__ __launch_bounds__(256) void tcvt_kernel(
    const float* __restrict__ w0, const float* __restrict__ w1, const float* __restrict__ w2,
    short* __restrict__ o0, short* __restrict__ o1, short* __restrict__ o2) {
  __shared__ short tile[64][65];
  const int bz = blockIdx.z;
  const float* in; short* out;
  if (bz < 8)       { in = w0; out = o0; }
  else if (bz < 16) { in = w1; out = o1; }
  else              { in = w2; out = o2; }
  const int ex = bz & 7;
  const float* src = in + (size_t)ex * DD * MM;
  short* dst = out + (size_t)ex * DD * MM;
  const int r0 = blockIdx.y * 64;
  const int c0 = blockIdx.x * 64;
  const int t = threadIdx.x;
  const int rr = t >> 4, cc = (t & 15) * 4;
  #pragma unroll
  for (int i = 0; i < 4; i++) {
    int row = rr + i * 16;
    f32x4 v = *(const f32x4*)(src + (size_t)(r0 + row) * MM + c0 + cc);
    tile[cc + 0][row] = f2bf(v[0]);
    tile[cc + 1][row] = f2bf(v[1]);
    tile[cc + 2][row] = f2bf(v[2]);
    tile[cc + 3][row] = f2bf(v[3]);
  }
  __syncthreads();
  const int orow = t >> 2, c8 = (t & 3) * 16;
  s16x8 v0, v1;
  #pragma unroll
  for (int i = 0; i < 8; i++) { v0[i] = tile[orow][c8 + i]; v1[i] = tile[orow][c8 + 8 + i]; }
  short* dp = dst + (size_t)(c0 + orow) * DD + r0 + c8;
  *(s16x8*)(dp) = v0;
  *(s16x8*)(dp + 8) = v1;
}

// ---------------- gate: fp32 logits, top-2, softmax ----------------
__global__ __launch_bounds__(256) void gate_kernel(const float* __restrict__ x,
    const float* __restrict__ gk, int* __restrict__ counts,
    int* __restrict__ tkidx, float* __restrict__ tkw) {
  int t = blockIdx.x;
  const float* xr = x + (size_t)t * DD;
  float acc[NE];
  #pragma unroll
  for (int e = 0; e < NE; e++) acc[e] = 0.f;
  for (int d = threadIdx.x; d < DD; d += 256) {
    float xv = xr[d];
    const float* g = gk + (size_t)d * NE;
    #pragma unroll
    for (int e = 0; e < NE; e++) acc[e] += xv * g[e];
  }
  #pragma unroll
  for (int e = 0; e < NE; e++) {
    #pragma unroll
    for (int off = 32; off >= 1; off >>= 1)
      acc[e] += __shfl_xor(acc[e], off, 64);
  }
  __shared__ float red[4][NE];
  int wid = threadIdx.x >> 6;
  int lane = threadIdx.x & 63;
  if (lane == 0) {
    #pragma unroll
    for (int e = 0; e < NE; e++) red[wid][e] = acc[e];
  }
  __syncthreads();
  if (threadIdx.x == 0) {
    float l[NE];
    #pragma unroll
    for (int e = 0; e < NE; e++) l[e] = red[0][e] + red[1][e] + red[2][e] + red[3][e];
    int i1 = 0; float v1 = l[0];
    #pragma unroll
    for (int e = 1; e < NE; e++) if (l[e] > v1) { v1 = l[e]; i1 = e; }
    int i2 = -1; float v2 = -1e30f;
    #pragma unroll
    for (int e = 0; e < NE; e++) if (e != i1 && l[e] > v2) { v2 = l[e]; i2 = e; }
    float p = __expf(v2 - v1);
    float inv = 1.f / (1.f + p);
    tkidx[t*2]   = i1; tkidx[t*2+1] = i2;
    tkw[t*2]     = inv; tkw[t*2+1]  = p * inv;
    atomicAdd(&counts[i1], 1);
    atomicAdd(&counts[i2], 1);
  }
}

// ---------------- scatter into per-expert compact lists (+ slot map) ----------------
__global__ __launch_bounds__(256) void scatter_kernel(const int* __restrict__ counts,
    int* __restrict__ offsets, const int* __restrict__ tkidx,
    const float* __restrict__ tkw, int* __restrict__ ltok, float* __restrict__ lwt,
    int* __restrict__ slots) {
  __shared__ int soff[NE];
  __shared__ int scur[NE];
  if (threadIdx.x == 0) {
    int s = 0;
    for (int e = 0; e < NE; e++) { offsets[e] = s; soff[e] = s; s += counts[e]; scur[e] = 0; }
    offsets[NE] = s;
  }
  __syncthreads();
  for (int i = threadIdx.x; i < TT * 2; i += 256) {
    int e = tkidx[i];
    int pos = atomicAdd(&scur[e], 1);
    int dst = soff[e] + pos;
    ltok[dst] = i >> 1;
    lwt[dst]  = tkw[i];
    slots[i]  = dst;
  }
}

// ---------------- combine: out[t] = comb[slot0] + comb[slot1] ----------------
__global__ __launch_bounds__(256) void combine_kernel(const float* __restrict__ comb,
    const int* __restrict__ slots, float* __restrict__ out) {
  const int t = blockIdx.x;
  const int s0 = slots[2 * t], s1 = slots[2 * t + 1];
  const f32x4* p0 = (const f32x4*)(comb + (size_t)s0 * DD);
  const f32x4* p1 = (const f32x4*)(comb + (size_t)s1 * DD);
  f32x4* po = (f32x4*)(out + (size_t)t * DD);
  #pragma unroll
  for (int i = 0; i < 2; i++) {
    int idx = threadIdx.x + i * 256;
    po[idx] = p0[idx] + p1[idx];
  }
}

// ---------------- segment lookup ----------------
__device__ __forceinline__ void find_seg(const int* __restrict__ offsets, int tile, int bm,
                                         int& e, int& row0, int& rows, int& seg) {
  e = -1; row0 = 0; rows = 0; seg = 0;
  int accT = 0, prev = offsets[0];
  #pragma unroll
  for (int i = 0; i < NE; i++) {
    int nxt = offsets[i+1];
    int cnt = nxt - prev;
    int nt = (cnt + bm - 1) / bm;
    if (e < 0 && tile < accT + nt) { e = i; row0 = (tile - accT) * bm; rows = cnt; seg = prev; }
    accT += nt; prev = nxt;
  }
}

// XCD-chunked blockIdx swizzle (bijective: nwg % 8 == 0), x-fast decode.
__device__ __forceinline__ void xcd_map(int& tile, int& nyi) {
  const int nx = gridDim.x;
  const int nwg = nx * gridDim.y;
  const int bid = blockIdx.y * nx + blockIdx.x;
  const int cpx = nwg >> 3;
  const int s = (bid & 7) * cpx + (bid >> 3);
  tile = s % nx;
  nyi  = s / nx;
}

// ================= FAST PATH (round-3 structure + XCD swizzle) =================
// 128x128 tile, BK=64, 256 threads (2x2 waves, 64x64 wave tile, 4x4 16x16x32 frags).
// LDS linear [128][64] shorts; swizzle: short-offset s holds G[row][s ^ ((row&7)*8)].
#define MAXT_F 136

__global__ __launch_bounds__(256, 2) void gemm1_fast(
    const short* __restrict__ xbf,
    const short* __restrict__ w0t, const short* __restrict__ w1t,
    const int* __restrict__ offsets,
    const int* __restrict__ ltok, const float* __restrict__ lwt,
    short* __restrict__ hbuf) {
  __shared__ short As[128 * 64];
  __shared__ short B0s[128 * 64];
  __shared__ short B1s[128 * 64];
  __shared__ float w_s[128];

  int tile, nyi;
  xcd_map(tile, nyi);
  const int n0 = nyi * 128;
  int e, row0, rows, seg;
  find_seg(offsets, tile, 128, e, row0, rows, seg);
  if (e < 0) return;

  const int tid = threadIdx.x;
  const int lane = tid & 63, wid = tid >> 6;
  if (tid < 128) {
    int gr = row0 + tid;
    w_s[tid] = (gr < rows) ? lwt[seg + gr] : 0.f;
  }

  const int swz = ((lane & 7) ^ (lane >> 3)) * 8;   // pre-swizzled source offset (shorts)
  const short* abase[4];
  const short* b0base[4];
  const short* b1base[4];
  #pragma unroll
  for (int c = 0; c < 4; c++) {
    int chunk = wid * 4 + c;
    int r = chunk * 8 + (lane >> 3);
    int gr = row0 + r; if (gr >= rows) gr = rows - 1;
    int tok = ltok[seg + gr];
    abase[c]  = xbf + (size_t)tok * DD + swz;
    int n = n0 + r;
    b0base[c] = w0t + ((size_t)e * MM + n) * DD + swz;
    b1base[c] = w1t + ((size_t)e * MM + n) * DD + swz;
  }

  const int wr = wid >> 1, wc = wid & 1;
  const int lr = lane & 15;
  const int kq = (lane >> 4) * 8;

  f32x4 acc0[4][4], acc1[4][4];
  #pragma unroll
  for (int i = 0; i < 4; i++)
    #pragma unroll
    for (int j = 0; j < 4; j++) { acc0[i][j] = 0.f; acc1[i][j] = 0.f; }

  for (int k0 = 0; k0 < DD; k0 += 64) {
    #pragma unroll
    for (int c = 0; c < 4; c++) {
      int chunk = wid * 4 + c;
      gload_lds16(abase[c]  + k0, As  + chunk * 512);
      gload_lds16(b0base[c] + k0, B0s + chunk * 512);
      gload_lds16(b1base[c] + k0, B1s + chunk * 512);
    }
    __syncthreads();

    #pragma unroll
    for (int ks = 0; ks < 2; ks++) {
      s16x8 a[4], b0[4], b1[4];
      #pragma unroll
      for (int mi = 0; mi < 4; mi++) {
        int row = wr * 64 + mi * 16 + lr;
        int koff = (ks * 32 + kq) ^ ((row & 7) * 8);
        a[mi] = *(const s16x8*)&As[row * 64 + koff];
      }
      #pragma unroll
      for (int ni = 0; ni < 4; ni++) {
        int row = wc * 64 + ni * 16 + lr;
        int koff = (ks * 32 + kq) ^ ((row & 7) * 8);
        b0[ni] = *(const s16x8*)&B0s[row * 64 + koff];
        b1[ni] = *(const s16x8*)&B1s[row * 64 + koff];
      }
      #pragma unroll
      for (int mi = 0; mi < 4; mi++)
        #pragma unroll
        for (int ni = 0; ni < 4; ni++) {
          acc0[mi][ni] = __builtin_amdgcn_mfma_f32_16x16x32_bf16(a[mi], b0[ni], acc0[mi][ni], 0, 0, 0);
          acc1[mi][ni] = __builtin_amdgcn_mfma_f32_16x16x32_bf16(a[mi], b1[ni], acc1[mi][ni], 0, 0, 0);
        }
    }
    __syncthreads();
  }

  const int lq = lane >> 4;
  #pragma unroll
  for (int mi = 0; mi < 4; mi++) {
    #pragma unroll
    for (int jj = 0; jj < 4; jj++) {
      int r = wr * 64 + mi * 16 + lq * 4 + jj;
      int gr = row0 + r;
      if (gr < rows) {
        float wgt = w_s[r];
        size_t hrow = (size_t)(seg + gr) * MM + n0;
        #pragma unroll
        for (int ni = 0; ni < 4; ni++) {
          int c = wc * 64 + ni * 16 + lr;
          float g = acc0[mi][ni][jj];
          float u = acc1[mi][ni][jj];
          float act = g / (1.f + __expf(-g));
          hbuf[hrow + c] = f2bf(act * u * wgt);
        }
      }
    }
  }
}

__global__ __launch_bounds__(256, 2) void gemm2_fast(
    const short* __restrict__ hbuf,
    const short* __restrict__ wot,
    const int* __restrict__ offsets,
    float* __restrict__ comb) {
  __shared__ short As[128 * 64];
  __shared__ short Bs[128 * 64];

  int tile, nyi;
  xcd_map(tile, nyi);
  const int n0 = nyi * 128;
  int e, row0, rows, seg;
  find_seg(offsets, tile, 128, e, row0, rows, seg);
  if (e < 0) return;

  const int tid = threadIdx.x;
  const int lane = tid & 63, wid = tid >> 6;

  const int swz = ((lane & 7) ^ (lane >> 3)) * 8;
  const short* abase[4];
  const short* bbase[4];
  #pragma unroll
  for (int c = 0; c < 4; c++) {
    int chunk = wid * 4 + c;
    int r = chunk * 8 + (lane >> 3);
    int gr = row0 + r; if (gr >= rows) gr = rows - 1;
    abase[c] = hbuf + (size_t)(seg + gr) * MM + swz;
    int n = n0 + r;
    bbase[c] = wot + ((size_t)e * DD + n) * MM + swz;
  }

  const int wr = wid >> 1, wc = wid & 1;
  const int lr = lane & 15;
  const int kq = (lane >> 4) * 8;

  f32x4 acc[4][4];
  #pragma unroll
  for (int i = 0; i < 4; i++)
    #pragma unroll
    for (int j = 0; j < 4; j++) acc[i][j] = 0.f;

  for (int k0 = 0; k0 < MM; k0 += 64) {
    #pragma unroll
    for (int c = 0; c < 4; c++) {
      int chunk = wid * 4 + c;
      gload_lds16(abase[c] + k0, As + chunk * 512);
      gload_lds16(bbase[c] + k0, Bs + chunk * 512);
    }
    __syncthreads();

    #pragma unroll
    for (int ks = 0; ks < 2; ks++) {
      s16x8 a[4], b[4];
      #pragma unroll
      for (int mi = 0; mi < 4; mi++) {
        int row = wr * 64 + mi * 16 + lr;
        int koff = (ks * 32 + kq) ^ ((row & 7) * 8);
        a[mi] = *(const s16x8*)&As[row * 64 + koff];
      }
      #pragma unroll
      for (int ni = 0; ni < 4; ni++) {
        int row = wc * 64 + ni * 16 + lr;
        int koff = (ks * 32 + kq) ^ ((row & 7) * 8);
        b[ni] = *(const s16x8*)&Bs[row * 64 + koff];
      }
      #pragma unroll
      for (int mi = 0; mi < 4; mi++)
        #pragma unroll
        for (int ni = 0; ni < 4; ni++)
          acc[mi][ni] = __builtin_amdgcn_mfma_f32_16x16x32_bf16(a[mi], b[ni], acc[mi][ni], 0, 0, 0);
    }
    __syncthreads();
  }

  const int lq = lane >> 4;
  #pragma unroll
  for (int mi = 0; mi < 4; mi++) {
    #pragma unroll
    for (int jj = 0; jj < 4; jj++) {
      int r = wr * 64 + mi * 16 + lq * 4 + jj;
      int gr = row0 + r;
      if (gr < rows) {
        size_t orow = (size_t)(seg + gr) * DD + n0;
        #pragma unroll
        for (int ni = 0; ni < 4; ni++) {
          int c = wc * 64 + ni * 16 + lr;
          comb[orow + c] = acc[mi][ni][jj];
        }
      }
    }
  }
}

// ---------------- launcher ----------------
extern "C" void kernel_launch(void* const* d_in, const int* in_sizes, int n_in,
                              void* d_out, int out_size, void* d_ws, size_t ws_size,
                              hipStream_t stream) {
  const float* x   = (const float*)d_in[0];
  const float* gk  = (const float*)d_in[1];
  const float* wi0 = (const float*)d_in[2];
  const float* wi1 = (const float*)d_in[3];
  const float* wo  = (const float*)d_in[4];
  float* out = (float*)d_out;

  char* w = (char*)d_ws;
  int*   counts  = (int*)(w);
  int*   offsets = (int*)(w + 256);
  int*   tkidx   = (int*)(w + 1024);
  float* tkw     = (float*)(w + 1024 + 65536);
  int*   ltok    = (int*)(w + 1024 + 2*65536);
  float* lwt     = (float*)(w + 1024 + 3*65536);
  int*   slots   = (int*)(w + 1024 + 4*65536);
  short* xbf  = (short*)(w + 524288);
  short* hbuf = xbf + (size_t)TT * DD;                     // 2T x M bf16
  short* w0t  = hbuf + (size_t)2 * TT * MM;
  short* w1t  = w0t + (size_t)NE * DD * MM;
  short* wot  = w1t + (size_t)NE * DD * MM;
  float* comb = (float*)w0t;   // reuse w0t+w1t region (128 MB) after gemm1

  hipMemsetAsync(counts, 0, 64, stream);

  cvt_kernel<<<1024, 256, 0, stream>>>(x, xbf, (size_t)TT * DD);
  gate_kernel<<<TT, 256, 0, stream>>>(x, gk, counts, tkidx, tkw);
  scatter_kernel<<<1, 256, 0, stream>>>(counts, offsets, tkidx, tkw, ltok, lwt, slots);
  tcvt_kernel<<<dim3(MM/64, DD/64, 24), 256, 0, stream>>>(wi0, wi1, wo, w0t, w1t, wot);

  gemm1_fast<<<dim3(MAXT_F, MM/128), 256, 0, stream>>>(xbf, w0t, w1t, offsets, ltok, lwt, hbuf);
  gemm2_fast<<<dim3(MAXT_F, DD/128), 256, 0, stream>>>(hbuf, wot, offsets, comb);
  combine_kernel<<<TT, 256, 0, stream>>>(comb, slots, out);
}

// Round 10
// 904.015 us; speedup vs baseline: 1.6562x; 1.0078x over previous
//
#include <hip/hip_runtime.h>
#include <hip/hip_bf16.h>
#include <stdint.h>

#define TT   8192   // B*S tokens
#define DD   2048
#define MM   2048
#define NE   8

typedef float f32x4 __attribute__((ext_vector_type(4)));
typedef short s16x8 __attribute__((ext_vector_type(8)));
typedef unsigned int u32;

static __device__ __forceinline__ short f2bf(float f) {
  __hip_bfloat16 h = __float2bfloat16(f);
  short s;
  __builtin_memcpy(&s, &h, 2);
  return s;
}

static __device__ __forceinline__ void gload_lds16(const short* g, short* lds) {
  __builtin_amdgcn_global_load_lds(
      (const __attribute__((address_space(1))) u32*)g,
      (__attribute__((address_space(3))) u32*)lds, 16, 0, 0);
}

// ---------------- fp32 -> bf16 transposing conversion (weights) ----------------
__global__ __launch_bounds__(256) void tcvt_kernel(
    const float* __restrict__ w0, const float* __restrict__ w1, const float* __restrict__ w2,
    short* __restrict__ o0, short* __restrict__ o1, short* __restrict__ o2) {
  __shared__ short tile[64][65];
  const int bz = blockIdx.z;
  const float* in; short* out;
  if (bz < 8)       { in = w0; out = o0; }
  else if (bz < 16) { in = w1; out = o1; }
  else              { in = w2; out = o2; }
  const int ex = bz & 7;
  const float* src = in + (size_t)ex * DD * MM;
  short* dst = out + (size_t)ex * DD * MM;
  const int r0 = blockIdx.y * 64;
  const int c0 = blockIdx.x * 64;
  const int t = threadIdx.x;
  const int rr = t >> 4, cc = (t & 15) * 4;
  #pragma unroll
  for (int i = 0; i < 4; i++) {
    int row = rr + i * 16;
    f32x4 v = *(const f32x4*)(src + (size_t)(r0 + row) * MM + c0 + cc);
    tile[cc + 0][row] = f2bf(v[0]);
    tile[cc + 1][row] = f2bf(v[1]);
    tile[cc + 2][row] = f2bf(v[2]);
    tile[cc + 3][row] = f2bf(v[3]);
  }
  __syncthreads();
  const int orow = t >> 2, c8 = (t & 3) * 16;
  s16x8 v0, v1;
  #pragma unroll
  for (int i = 0; i < 8; i++) { v0[i] = tile[orow][c8 + i]; v1[i] = tile[orow][c8 + 8 + i]; }
  short* dp = dst + (size_t)(c0 + orow) * DD + r0 + c8;
  *(s16x8*)(dp) = v0;
  *(s16x8*)(dp + 8) = v1;
}

// ---------------- fused gate + x cvt: fp32 logits, top-2, softmax; writes xbf ----------------
__global__ __launch_bounds__(256) void gate_kernel(const float* __restrict__ x,
    const float* __restrict__ gk, int* __restrict__ counts,
    int* __restrict__ tkidx, float* __restrict__ tkw, short* __restrict__ xbf) {
  int t = blockIdx.x;
  const float* xr = x + (size_t)t * DD;
  const int d0 = threadIdx.x * 8;
  f32x4 a = *(const f32x4*)(xr + d0);
  f32x4 b = *(const f32x4*)(xr + d0 + 4);
  s16x8 v;
  v[0]=f2bf(a[0]); v[1]=f2bf(a[1]); v[2]=f2bf(a[2]); v[3]=f2bf(a[3]);
  v[4]=f2bf(b[0]); v[5]=f2bf(b[1]); v[6]=f2bf(b[2]); v[7]=f2bf(b[3]);
  *(s16x8*)(xbf + (size_t)t * DD + d0) = v;

  float acc[NE];
  #pragma unroll
  for (int e = 0; e < NE; e++) acc[e] = 0.f;
  #pragma unroll
  for (int j = 0; j < 8; j++) {
    float xv = (j < 4) ? a[j] : b[j - 4];
    const float* g = gk + (size_t)(d0 + j) * NE;
    #pragma unroll
    for (int e = 0; e < NE; e++) acc[e] += xv * g[e];
  }
  #pragma unroll
  for (int e = 0; e < NE; e++) {
    #pragma unroll
    for (int off = 32; off >= 1; off >>= 1)
      acc[e] += __shfl_xor(acc[e], off, 64);
  }
  __shared__ float red[4][NE];
  int wid = threadIdx.x >> 6;
  int lane = threadIdx.x & 63;
  if (lane == 0) {
    #pragma unroll
    for (int e = 0; e < NE; e++) red[wid][e] = acc[e];
  }
  __syncthreads();
  if (threadIdx.x == 0) {
    float l[NE];
    #pragma unroll
    for (int e = 0; e < NE; e++) l[e] = red[0][e] + red[1][e] + red[2][e] + red[3][e];
    int i1 = 0; float v1 = l[0];
    #pragma unroll
    for (int e = 1; e < NE; e++) if (l[e] > v1) { v1 = l[e]; i1 = e; }
    int i2 = -1; float v2 = -1e30f;
    #pragma unroll
    for (int e = 0; e < NE; e++) if (e != i1 && l[e] > v2) { v2 = l[e]; i2 = e; }
    float p = __expf(v2 - v1);
    float inv = 1.f / (1.f + p);
    tkidx[t*2]   = i1; tkidx[t*2+1] = i2;
    tkw[t*2]     = inv; tkw[t*2+1]  = p * inv;
    atomicAdd(&counts[i1], 1);
    atomicAdd(&counts[i2], 1);
  }
}

// ---------------- scatter into per-expert compact lists (+ slot map) ----------------
__global__ __launch_bounds__(256) void scatter_kernel(const int* __restrict__ counts,
    int* __restrict__ offsets, const int* __restrict__ tkidx,
    const float* __restrict__ tkw, int* __restrict__ ltok, float* __restrict__ lwt,
    int* __restrict__ slots) {
  __shared__ int soff[NE];
  __shared__ int scur[NE];
  if (threadIdx.x == 0) {
    int s = 0;
    for (int e = 0; e < NE; e++) { offsets[e] = s; soff[e] = s; s += counts[e]; scur[e] = 0; }
    offsets[NE] = s;
  }
  __syncthreads();
  for (int i = threadIdx.x; i < TT * 2; i += 256) {
    int e = tkidx[i];
    int pos = atomicAdd(&scur[e], 1);
    int dst = soff[e] + pos;
    ltok[dst] = i >> 1;
    lwt[dst]  = tkw[i];
    slots[i]  = dst;
  }
}

// ---------------- combine: out[t] = comb[slot0] + comb[slot1] ----------------
__global__ __launch_bounds__(256) void combine_kernel(const float* __restrict__ comb,
    const int* __restrict__ slots, float* __restrict__ out) {
  const int t = blockIdx.x;
  const int s0 = slots[2 * t], s1 = slots[2 * t + 1];
  const f32x4* p0 = (const f32x4*)(comb + (size_t)s0 * DD);
  const f32x4* p1 = (const f32x4*)(comb + (size_t)s1 * DD);
  f32x4* po = (f32x4*)(out + (size_t)t * DD);
  #pragma unroll
  for (int i = 0; i < 2; i++) {
    int idx = threadIdx.x + i * 256;
    po[idx] = p0[idx] + p1[idx];
  }
}

// ---------------- segment lookup ----------------
__device__ __forceinline__ void find_seg(const int* __restrict__ offsets, int tile, int bm,
                                         int& e, int& row0, int& rows, int& seg) {
  e = -1; row0 = 0; rows = 0; seg = 0;
  int accT = 0, prev = offsets[0];
  #pragma unroll
  for (int i = 0; i < NE; i++) {
    int nxt = offsets[i+1];
    int cnt = nxt - prev;
    int nt = (cnt + bm - 1) / bm;
    if (e < 0 && tile < accT + nt) { e = i; row0 = (tile - accT) * bm; rows = cnt; seg = prev; }
    accT += nt; prev = nxt;
  }
}

// XCD-chunked blockIdx swizzle (bijective: nwg % 8 == 0), x-fast decode.
__device__ __forceinline__ void xcd_map(int& tile, int& nyi) {
  const int nx = gridDim.x;
  const int nwg = nx * gridDim.y;
  const int bid = blockIdx.y * nx + blockIdx.x;
  const int cpx = nwg >> 3;
  const int s = (bid & 7) * cpx + (bid >> 3);
  tile = s % nx;
  nyi  = s / nx;
}

// ================= GEMM kernels: 128-row tile, dual 128-col B, BK=64 =================
// 256 threads (2x2 waves, 64x64 wave tile, 4x4 16x16x32 frags per B matrix).
// LDS linear [128][64] shorts; swizzle: short-offset s holds G[row][s ^ ((row&7)*8)].
#define MAXT_F 136

__global__ __launch_bounds__(256, 2) void gemm1_fast(
    const short* __restrict__ xbf,
    const short* __restrict__ w0t, const short* __restrict__ w1t,
    const int* __restrict__ offsets,
    const int* __restrict__ ltok, const float* __restrict__ lwt,
    short* __restrict__ hbuf) {
  __shared__ short As[128 * 64];
  __shared__ short B0s[128 * 64];
  __shared__ short B1s[128 * 64];
  __shared__ float w_s[128];

  int tile, nyi;
  xcd_map(tile, nyi);
  const int n0 = nyi * 128;
  int e, row0, rows, seg;
  find_seg(offsets, tile, 128, e, row0, rows, seg);
  if (e < 0) return;

  const int tid = threadIdx.x;
  const int lane = tid & 63, wid = tid >> 6;
  if (tid < 128) {
    int gr = row0 + tid;
    w_s[tid] = (gr < rows) ? lwt[seg + gr] : 0.f;
  }

  const int swz = ((lane & 7) ^ (lane >> 3)) * 8;   // pre-swizzled source offset (shorts)
  const short* abase[4];
  const short* b0base[4];
  const short* b1base[4];
  #pragma unroll
  for (int c = 0; c < 4; c++) {
    int chunk = wid * 4 + c;
    int r = chunk * 8 + (lane >> 3);
    int gr = row0 + r; if (gr >= rows) gr = rows - 1;
    int tok = ltok[seg + gr];
    abase[c]  = xbf + (size_t)tok * DD + swz;
    int n = n0 + r;
    b0base[c] = w0t + ((size_t)e * MM + n) * DD + swz;
    b1base[c] = w1t + ((size_t)e * MM + n) * DD + swz;
  }

  const int wr = wid >> 1, wc = wid & 1;
  const int lr = lane & 15;
  const int kq = (lane >> 4) * 8;

  f32x4 acc0[4][4], acc1[4][4];
  #pragma unroll
  for (int i = 0; i < 4; i++)
    #pragma unroll
    for (int j = 0; j < 4; j++) { acc0[i][j] = 0.f; acc1[i][j] = 0.f; }

  for (int k0 = 0; k0 < DD; k0 += 64) {
    #pragma unroll
    for (int c = 0; c < 4; c++) {
      int chunk = wid * 4 + c;
      gload_lds16(abase[c]  + k0, As  + chunk * 512);
      gload_lds16(b0base[c] + k0, B0s + chunk * 512);
      gload_lds16(b1base[c] + k0, B1s + chunk * 512);
    }
    __syncthreads();

    #pragma unroll
    for (int ks = 0; ks < 2; ks++) {
      s16x8 a[4], b0[4], b1[4];
      #pragma unroll
      for (int mi = 0; mi < 4; mi++) {
        int row = wr * 64 + mi * 16 + lr;
        int koff = (ks * 32 + kq) ^ ((row & 7) * 8);
        a[mi] = *(const s16x8*)&As[row * 64 + koff];
      }
      #pragma unroll
      for (int ni = 0; ni < 4; ni++) {
        int row = wc * 64 + ni * 16 + lr;
        int koff = (ks * 32 + kq) ^ ((row & 7) * 8);
        b0[ni] = *(const s16x8*)&B0s[row * 64 + koff];
        b1[ni] = *(const s16x8*)&B1s[row * 64 + koff];
      }
      #pragma unroll
      for (int mi = 0; mi < 4; mi++)
        #pragma unroll
        for (int ni = 0; ni < 4; ni++) {
          acc0[mi][ni] = __builtin_amdgcn_mfma_f32_16x16x32_bf16(a[mi], b0[ni], acc0[mi][ni], 0, 0, 0);
          acc1[mi][ni] = __builtin_amdgcn_mfma_f32_16x16x32_bf16(a[mi], b1[ni], acc1[mi][ni], 0, 0, 0);
        }
    }
    __syncthreads();
  }

  const int lq = lane >> 4;
  #pragma unroll
  for (int mi = 0; mi < 4; mi++) {
    #pragma unroll
    for (int jj = 0; jj < 4; jj++) {
      int r = wr * 64 + mi * 16 + lq * 4 + jj;
      int gr = row0 + r;
      if (gr < rows) {
        float wgt = w_s[r];
        size_t hrow = (size_t)(seg + gr) * MM + n0;
        #pragma unroll
        for (int ni = 0; ni < 4; ni++) {
          int c = wc * 64 + ni * 16 + lr;
          float g = acc0[mi][ni][jj];
          float u = acc1[mi][ni][jj];
          float act = g / (1.f + __expf(-g));
          hbuf[hrow + c] = f2bf(act * u * wgt);
        }
      }
    }
  }
}

// gemm2: identical structure; B0/B1 are two adjacent 128-col slices of wot (BN=256 total).
__global__ __launch_bounds__(256, 2) void gemm2_fast(
    const short* __restrict__ hbuf,
    const short* __restrict__ wot,
    const int* __restrict__ offsets,
    float* __restrict__ comb) {
  __shared__ short As[128 * 64];
  __shared__ short B0s[128 * 64];
  __shared__ short B1s[128 * 64];

  int tile, nyi;
  xcd_map(tile, nyi);
  const int n0 = nyi * 256;
  int e, row0, rows, seg;
  find_seg(offsets, tile, 128, e, row0, rows, seg);
  if (e < 0) return;

  const int tid = threadIdx.x;
  const int lane = tid & 63, wid = tid >> 6;

  const int swz = ((lane & 7) ^ (lane >> 3)) * 8;
  const short* abase[4];
  const short* b0base[4];
  const short* b1base[4];
  #pragma unroll
  for (int c = 0; c < 4; c++) {
    int chunk = wid * 4 + c;
    int r = chunk * 8 + (lane >> 3);
    int gr = row0 + r; if (gr >= rows) gr = rows - 1;
    abase[c] = hbuf + (size_t)(seg + gr) * MM + swz;
    b0base[c] = wot + ((size_t)e * DD + n0 + r) * MM + swz;
    b1base[c] = wot + ((size_t)e * DD + n0 + 128 + r) * MM + swz;
  }

  const int wr = wid >> 1, wc = wid & 1;
  const int lr = lane & 15;
  const int kq = (lane >> 4) * 8;

  f32x4 acc0[4][4], acc1[4][4];
  #pragma unroll
  for (int i = 0; i < 4; i++)
    #pragma unroll
    for (int j = 0; j < 4; j++) { acc0[i][j] = 0.f; acc1[i][j] = 0.f; }

  for (int k0 = 0; k0 < MM; k0 += 64) {
    #pragma unroll
    for (int c = 0; c < 4; c++) {
      int chunk = wid * 4 + c;
      gload_lds16(abase[c]  + k0, As  + chunk * 512);
      gload_lds16(b0base[c] + k0, B0s + chunk * 512);
      gload_lds16(b1base[c] + k0, B1s + chunk * 512);
    }
    __syncthreads();

    #pragma unroll
    for (int ks = 0; ks < 2; ks++) {
      s16x8 a[4], b0[4], b1[4];
      #pragma unroll
      for (int mi = 0; mi < 4; mi++) {
        int row = wr * 64 + mi * 16 + lr;
        int koff = (ks * 32 + kq) ^ ((row & 7) * 8);
        a[mi] = *(const s16x8*)&As[row * 64 + koff];
      }
      #pragma unroll
      for (int ni = 0; ni < 4; ni++) {
        int row = wc * 64 + ni * 16 + lr;
        int koff = (ks * 32 + kq) ^ ((row & 7) * 8);
        b0[ni] = *(const s16x8*)&B0s[row * 64 + koff];
        b1[ni] = *(const s16x8*)&B1s[row * 64 + koff];
      }
      #pragma unroll
      for (int mi = 0; mi < 4; mi++)
        #pragma unroll
        for (int ni = 0; ni < 4; ni++) {
          acc0[mi][ni] = __builtin_amdgcn_mfma_f32_16x16x32_bf16(a[mi], b0[ni], acc0[mi][ni], 0, 0, 0);
          acc1[mi][ni] = __builtin_amdgcn_mfma_f32_16x16x32_bf16(a[mi], b1[ni], acc1[mi][ni], 0, 0, 0);
        }
    }
    __syncthreads();
  }

  const int lq = lane >> 4;
  #pragma unroll
  for (int mi = 0; mi < 4; mi++) {
    #pragma unroll
    for (int jj = 0; jj < 4; jj++) {
      int r = wr * 64 + mi * 16 + lq * 4 + jj;
      int gr = row0 + r;
      if (gr < rows) {
        size_t orow = (size_t)(seg + gr) * DD + n0;
        #pragma unroll
        for (int ni = 0; ni < 4; ni++) {
          int c = wc * 64 + ni * 16 + lr;
          comb[orow + c] = acc0[mi][ni][jj];
          comb[orow + 128 + c] = acc1[mi][ni][jj];
        }
      }
    }
  }
}

// ---------------- launcher ----------------
extern "C" void kernel_launch(void* const* d_in, const int* in_sizes, int n_in,
                              void* d_out, int out_size, void* d_ws, size_t ws_size,
                              hipStream_t stream) {
  const float* x   = (const float*)d_in[0];
  const float* gk  = (const float*)d_in[1];
  const float* wi0 = (const float*)d_in[2];
  const float* wi1 = (const float*)d_in[3];
  const float* wo  = (const float*)d_in[4];
  float* out = (float*)d_out;

  char* w = (char*)d_ws;
  int*   counts  = (int*)(w);
  int*   offsets = (int*)(w + 256);
  int*   tkidx   = (int*)(w + 1024);
  float* tkw     = (float*)(w + 1024 + 65536);
  int*   ltok    = (int*)(w + 1024 + 2*65536);
  float* lwt     = (float*)(w + 1024 + 3*65536);
  int*   slots   = (int*)(w + 1024 + 4*65536);
  short* xbf  = (short*)(w + 524288);
  short* hbuf = xbf + (size_t)TT * DD;                     // 2T x M bf16
  short* w0t  = hbuf + (size_t)2 * TT * MM;
  short* w1t  = w0t + (size_t)NE * DD * MM;
  short* wot  = w1t + (size_t)NE * DD * MM;
  float* comb = (float*)w0t;   // reuse w0t+w1t region (128 MB) after gemm1

  hipMemsetAsync(counts, 0, 64, stream);

  gate_kernel<<<TT, 256, 0, stream>>>(x, gk, counts, tkidx, tkw, xbf);
  scatter_kernel<<<1, 256, 0, stream>>>(counts, offsets, tkidx, tkw, ltok, lwt, slots);
  tcvt_kernel<<<dim3(MM/64, DD/64, 24), 256, 0, stream>>>(wi0, wi1, wo, w0t, w1t, wot);

  gemm1_fast<<<dim3(MAXT_F, MM/128), 256, 0, stream>>>(xbf, w0t, w1t, offsets, ltok, lwt, hbuf);
  gemm2_fast<<<dim3(MAXT_F, DD/256), 256, 0, stream>>>(hbuf, wot, offsets, comb);
  combine_kernel<<<TT, 256, 0, stream>>>(comb, slots, out);
}